// Round 4
// baseline (198.945 us; speedup 1.0000x reference)
//
#include <hip/hip_runtime.h>

// Problem constants (from reference setup_inputs)
constexpr int Bc = 8;
constexpr int Nc = 300;
constexpr int Cc = 256;
constexpr int Pc = 32;

typedef float f32x4 __attribute__((ext_vector_type(4)));

// Level geometry
__constant__ int c_HW[4] = {100, 50, 25, 13};
// floats per slice: 10000, 2500, 625, 169 ; LDS offsets (floats)
constexpr int LVL_N[4]   = {10000, 2500, 625, 169};
constexpr int LVL_OFF[4] = {0, 10000, 12500, 13125};
constexpr int LDS_FLOATS = 13294;   // 53,176 B

// ---------------------------------------------------------------------------
// Kernel 1: per-query params. One block per query q = b*N+n.
// params[q*8 + {0:sx, 1:sy, 2..5: zw[l]}]
// ---------------------------------------------------------------------------
__global__ __launch_bounds__(256) void params_kernel(
    const float* __restrict__ qpos, const float* __restrict__ qcont,
    const float* __restrict__ Woff, const float* __restrict__ boff,
    const float* __restrict__ sigma, float* __restrict__ params)
{
    const int q = blockIdx.x;
    const int c = threadIdx.x;
    float qc = qcont[q * Cc + c];
    float p0 = qc * Woff[c * 3 + 0];
    float p1 = qc * Woff[c * 3 + 1];
    float p2 = qc * Woff[c * 3 + 2];
#pragma unroll
    for (int off = 32; off > 0; off >>= 1) {
        p0 += __shfl_down(p0, off, 64);
        p1 += __shfl_down(p1, off, 64);
        p2 += __shfl_down(p2, off, 64);
    }
    __shared__ float red[4][3];
    const int wave = threadIdx.x >> 6;
    if ((threadIdx.x & 63) == 0) {
        red[wave][0] = p0; red[wave][1] = p1; red[wave][2] = p2;
    }
    __syncthreads();
    if (threadIdx.x == 0) {
        float dx = red[0][0] + red[1][0] + red[2][0] + red[3][0] + boff[0];
        float dy = red[0][1] + red[1][1] + red[2][1] + red[3][1] + boff[1];
        float dz = red[0][2] + red[1][2] + red[2][2] + red[3][2] + boff[2];
        float x = qpos[q * 4 + 0];
        float y = qpos[q * 4 + 1];
        float z = qpos[q * 4 + 2];
        float r = qpos[q * 4 + 3];
        float sx = x + dx * exp2f(z - r);
        float sy = y + dy * exp2f(z + r);
        float sz = z + dz;
        float sg = sigma[0];
        float inv = 1.0f / (2.0f * sg * sg);
        float e[4];
        float s = 0.f;
#pragma unroll
        for (int l = 0; l < 4; ++l) {
            float d = sz - (float)l;
            float w = __expf(-d * d * inv);   // gaussian weight in (0,1]
            e[l] = __expf(w);                 // softmax numerator of that weight
            s += e[l];
        }
        float rs = 1.0f / s;
        params[q * 8 + 0] = sx;
        params[q * 8 + 1] = sy;
#pragma unroll
        for (int l = 0; l < 4; ++l) params[q * 8 + 2 + l] = e[l] * rs;
    }
}

// ---------------------------------------------------------------------------
// Kernel 2: one block per (b,c). Stream the 4 feature slices into LDS
// (coalesced), then answer all 300 queries from LDS.
// outT[(b*Cc + c)*Nc + n]  <- coalesced writes (thread index = n)
// ---------------------------------------------------------------------------
__global__ __launch_bounds__(256) void sample_kernel(
    const float* __restrict__ f0, const float* __restrict__ f1,
    const float* __restrict__ f2, const float* __restrict__ f3,
    const float* __restrict__ params, float* __restrict__ outT)
{
    __shared__ float sl[LDS_FLOATS];
    const int bc = blockIdx.x;           // b*Cc + c
    const int t = threadIdx.x;

    // ---- stage slices into LDS ----
    // level 0: 10000 floats, slice byte offset = bc*40000 (16B aligned) -> vec4
    {
        const f32x4* src = (const f32x4*)(f0 + (size_t)bc * 10000);
        f32x4* dst = (f32x4*)&sl[LVL_OFF[0]];
        for (int i = t; i < 2500; i += 256) dst[i] = src[i];
    }
    // level 1: 2500 floats, byte offset = bc*10000 (16B aligned) -> vec4
    {
        const f32x4* src = (const f32x4*)(f1 + (size_t)bc * 2500);
        f32x4* dst = (f32x4*)&sl[LVL_OFF[1]];
        for (int i = t; i < 625; i += 256) dst[i] = src[i];
    }
    // level 2: 625 floats (odd offset -> dword copy)
    {
        const float* src = f2 + (size_t)bc * 625;
        float* dst = &sl[LVL_OFF[2]];
        for (int i = t; i < 625; i += 256) dst[i] = src[i];
    }
    // level 3: 169 floats (dword copy)
    {
        const float* src = f3 + (size_t)bc * 169;
        float* dst = &sl[LVL_OFF[3]];
        if (t < 169) dst[t] = src[t];
    }
    __syncthreads();

    // ---- answer queries from LDS ----
    const int b = bc >> 8;               // bc / Cc
    for (int n = t; n < Nc; n += 256) {
        const int q = b * Nc + n;
        const float sx = params[q * 8 + 0];
        const float sy = params[q * 8 + 1];
        float acc = 0.f;
#pragma unroll
        for (int l = 0; l < 4; ++l) {
            const int W = c_HW[l];
            const float zw = params[q * 8 + 2 + l];
            float px = fminf(fmaxf(sx - 0.5f, 0.f), (float)(W - 1));
            float py = fminf(fmaxf(sy - 0.5f, 0.f), (float)(W - 1));
            float x0f = floorf(px);
            float y0f = floorf(py);
            float wx = px - x0f;
            float wy = py - y0f;
            int x0 = (int)x0f;
            int y0 = (int)y0f;
            int x1 = min(x0 + 1, W - 1);
            int y1 = min(y0 + 1, W - 1);
            const float* base = &sl[LVL_OFF[l]];
            float v00 = base[y0 * W + x0];
            float v01 = base[y0 * W + x1];
            float v10 = base[y1 * W + x0];
            float v11 = base[y1 * W + x1];
            float top = v00 + wx * (v01 - v00);
            float bot = v10 + wx * (v11 - v10);
            acc += zw * (top + wy * (bot - top));
        }
        outT[(size_t)bc * Nc + n] = acc;
    }
}

// ---------------------------------------------------------------------------
// Kernel 3: one block per query. Read 256 channel values (strided dwords,
// L2/L3-absorbed: outT footprint 2.46 MB), broadcast over P with NT float4.
// ---------------------------------------------------------------------------
__global__ __launch_bounds__(256) void broadcast_kernel(
    const float* __restrict__ outT, float* __restrict__ out)
{
    __shared__ float sval[Cc];
    const int q = blockIdx.x;            // b*Nc + n
    const int b = q / Nc;
    const int n = q - b * Nc;
    const int c = threadIdx.x;
    sval[c] = outT[((size_t)(b * Cc + c)) * Nc + n];
    __syncthreads();

    const int wave = threadIdx.x >> 6;
    const int c4 = (threadIdx.x & 63) * 4;
    f32x4 val = *(const f32x4*)&sval[c4];
    float* obase = out + (size_t)q * (Pc * Cc) + c4;
#pragma unroll
    for (int p = wave; p < Pc; p += 4) {
        __builtin_nontemporal_store(val, (f32x4*)(obase + p * Cc));
    }
}

// ---------------------------------------------------------------------------
// Fallback: the proven round-3 single-kernel path (if ws too small).
// ---------------------------------------------------------------------------
__global__ __launch_bounds__(256) void sampling3d_fallback(
    const float* __restrict__ f0, const float* __restrict__ f1,
    const float* __restrict__ f2, const float* __restrict__ f3,
    const float* __restrict__ qpos, const float* __restrict__ qcont,
    const float* __restrict__ Woff, const float* __restrict__ boff,
    const float* __restrict__ sigma, float* __restrict__ out)
{
    const int q = blockIdx.x;
    const int b = q / Nc;
    const int c = threadIdx.x;
    float qc = qcont[q * Cc + c];
    float p0 = qc * Woff[c * 3 + 0];
    float p1 = qc * Woff[c * 3 + 1];
    float p2 = qc * Woff[c * 3 + 2];
#pragma unroll
    for (int off = 32; off > 0; off >>= 1) {
        p0 += __shfl_down(p0, off, 64);
        p1 += __shfl_down(p1, off, 64);
        p2 += __shfl_down(p2, off, 64);
    }
    __shared__ float red[4][3];
    __shared__ float par[8];
    __shared__ float accs[Cc];
    const int wave = threadIdx.x >> 6;
    if ((threadIdx.x & 63) == 0) { red[wave][0] = p0; red[wave][1] = p1; red[wave][2] = p2; }
    __syncthreads();
    if (threadIdx.x == 0) {
        float dx = red[0][0] + red[1][0] + red[2][0] + red[3][0] + boff[0];
        float dy = red[0][1] + red[1][1] + red[2][1] + red[3][1] + boff[1];
        float dz = red[0][2] + red[1][2] + red[2][2] + red[3][2] + boff[2];
        float x = qpos[q * 4 + 0], y = qpos[q * 4 + 1];
        float z = qpos[q * 4 + 2], r = qpos[q * 4 + 3];
        float sx = x + dx * exp2f(z - r);
        float sy = y + dy * exp2f(z + r);
        float sz = z + dz;
        float sg = sigma[0];
        float inv = 1.0f / (2.0f * sg * sg);
        float e[4]; float s = 0.f;
#pragma unroll
        for (int l = 0; l < 4; ++l) {
            float d = sz - (float)l;
            float w = __expf(-d * d * inv);
            e[l] = __expf(w);
            s += e[l];
        }
        float rs = 1.0f / s;
        par[0] = sx; par[1] = sy;
#pragma unroll
        for (int l = 0; l < 4; ++l) par[2 + l] = e[l] * rs;
    }
    __syncthreads();
    const float sx = par[0];
    const float sy = par[1];
    const float* const fs[4] = {f0, f1, f2, f3};
    const int HWs[4] = {100, 50, 25, 13};
    float acc = 0.f;
#pragma unroll
    for (int l = 0; l < 4; ++l) {
        const int W = HWs[l];
        float px = fminf(fmaxf(sx - 0.5f, 0.f), (float)(W - 1));
        float py = fminf(fmaxf(sy - 0.5f, 0.f), (float)(W - 1));
        float x0f = floorf(px), y0f = floorf(py);
        float wx = px - x0f, wy = py - y0f;
        int x0 = (int)x0f, y0 = (int)y0f;
        int x1 = min(x0 + 1, W - 1), y1 = min(y0 + 1, W - 1);
        const float* base = fs[l] + (size_t)((b * Cc + c) * W) * W;
        float v00 = base[y0 * W + x0];
        float v01 = base[y0 * W + x1];
        float v10 = base[y1 * W + x0];
        float v11 = base[y1 * W + x1];
        float top = v00 + wx * (v01 - v00);
        float bot = v10 + wx * (v11 - v10);
        acc += par[2 + l] * (top + wy * (bot - top));
    }
    accs[c] = acc;
    __syncthreads();
    const int c4 = (threadIdx.x & 63) * 4;
    f32x4 val = *(const f32x4*)&accs[c4];
    float* obase = out + (size_t)q * (Pc * Cc) + c4;
#pragma unroll
    for (int p = wave; p < Pc; p += 4) {
        __builtin_nontemporal_store(val, (f32x4*)(obase + p * Cc));
    }
}

extern "C" void kernel_launch(void* const* d_in, const int* in_sizes, int n_in,
                              void* d_out, int out_size, void* d_ws, size_t ws_size,
                              hipStream_t stream) {
    const float* f0    = (const float*)d_in[0];
    const float* f1    = (const float*)d_in[1];
    const float* f2    = (const float*)d_in[2];
    const float* f3    = (const float*)d_in[3];
    const float* qpos  = (const float*)d_in[4];
    const float* qcont = (const float*)d_in[5];
    const float* Woff  = (const float*)d_in[6];
    const float* boff  = (const float*)d_in[7];
    const float* sigma = (const float*)d_in[8];
    float* out = (float*)d_out;

    const size_t params_bytes = (size_t)Bc * Nc * 8 * sizeof(float);      // 76.8 KB
    const size_t outT_bytes   = (size_t)Bc * Cc * Nc * sizeof(float);     // 2.46 MB

    if (ws_size >= params_bytes + outT_bytes) {
        float* params = (float*)d_ws;
        float* outT   = (float*)((char*)d_ws + params_bytes);
        params_kernel<<<Bc * Nc, 256, 0, stream>>>(qpos, qcont, Woff, boff, sigma, params);
        sample_kernel<<<Bc * Cc, 256, 0, stream>>>(f0, f1, f2, f3, params, outT);
        broadcast_kernel<<<Bc * Nc, 256, 0, stream>>>(outT, out);
    } else {
        sampling3d_fallback<<<Bc * Nc, 256, 0, stream>>>(
            f0, f1, f2, f3, qpos, qcont, Woff, boff, sigma, out);
    }
}

// Round 5
// 191.436 us; speedup vs baseline: 1.0392x; 1.0392x over previous
//
#include <hip/hip_runtime.h>

// Problem constants (from reference setup_inputs)
constexpr int Bc = 8;
constexpr int Nc = 300;
constexpr int Cc = 256;
constexpr int Pc = 32;

typedef float f32x4 __attribute__((ext_vector_type(4)));

// Level geometry: 100^2, 50^2, 25^2, 13^2 ; floats/slice 10000, 2500, 625, 169
constexpr int LVL_OFF[4] = {0, 10000, 12500, 13125};
constexpr int LDS_FLOATS = 13294;   // 53,176 B

// ---------------------------------------------------------------------------
// Kernel 1: per-query params. One block per query q = b*N+n.
// params[q*8 + {0:sx, 1:sy, 2..5: zw[l]}]
// ---------------------------------------------------------------------------
__global__ __launch_bounds__(256) void params_kernel(
    const float* __restrict__ qpos, const float* __restrict__ qcont,
    const float* __restrict__ Woff, const float* __restrict__ boff,
    const float* __restrict__ sigma, float* __restrict__ params)
{
    const int q = blockIdx.x;
    const int c = threadIdx.x;
    float qc = qcont[q * Cc + c];
    float p0 = qc * Woff[c * 3 + 0];
    float p1 = qc * Woff[c * 3 + 1];
    float p2 = qc * Woff[c * 3 + 2];
#pragma unroll
    for (int off = 32; off > 0; off >>= 1) {
        p0 += __shfl_down(p0, off, 64);
        p1 += __shfl_down(p1, off, 64);
        p2 += __shfl_down(p2, off, 64);
    }
    __shared__ float red[4][3];
    const int wave = threadIdx.x >> 6;
    if ((threadIdx.x & 63) == 0) {
        red[wave][0] = p0; red[wave][1] = p1; red[wave][2] = p2;
    }
    __syncthreads();
    if (threadIdx.x == 0) {
        float dx = red[0][0] + red[1][0] + red[2][0] + red[3][0] + boff[0];
        float dy = red[0][1] + red[1][1] + red[2][1] + red[3][1] + boff[1];
        float dz = red[0][2] + red[1][2] + red[2][2] + red[3][2] + boff[2];
        float x = qpos[q * 4 + 0];
        float y = qpos[q * 4 + 1];
        float z = qpos[q * 4 + 2];
        float r = qpos[q * 4 + 3];
        float sx = x + dx * exp2f(z - r);
        float sy = y + dy * exp2f(z + r);
        float sz = z + dz;
        float sg = sigma[0];
        float inv = 1.0f / (2.0f * sg * sg);
        float e[4];
        float s = 0.f;
#pragma unroll
        for (int l = 0; l < 4; ++l) {
            float d = sz - (float)l;
            float w = __expf(-d * d * inv);   // gaussian weight in (0,1]
            e[l] = __expf(w);                 // softmax numerator of that weight
            s += e[l];
        }
        float rs = 1.0f / s;
        params[q * 8 + 0] = sx;
        params[q * 8 + 1] = sy;
#pragma unroll
        for (int l = 0; l < 4; ++l) params[q * 8 + 2 + l] = e[l] * rs;
    }
}

// bilinear from an LDS slice, border padding, align_corners=False
__device__ __forceinline__ float lerp_lds(const float* __restrict__ base, int W,
                                          float sx, float sy)
{
    float px = fminf(fmaxf(sx - 0.5f, 0.f), (float)(W - 1));
    float py = fminf(fmaxf(sy - 0.5f, 0.f), (float)(W - 1));
    float x0f = floorf(px);
    float y0f = floorf(py);
    float wx = px - x0f;
    float wy = py - y0f;
    int x0 = (int)x0f;
    int y0 = (int)y0f;
    int x1 = min(x0 + 1, W - 1);
    int y1 = min(y0 + 1, W - 1);
    float v00 = base[y0 * W + x0];
    float v01 = base[y0 * W + x1];
    float v10 = base[y1 * W + x0];
    float v11 = base[y1 * W + x1];
    float top = v00 + wx * (v01 - v00);
    float bot = v10 + wx * (v11 - v10);
    return top + wy * (bot - top);
}

// ---------------------------------------------------------------------------
// Kernel 2: one block per (b,c). Stage the 4 feature slices into LDS with
// load-ALL-then-store-ALL (fully unrolled -> ~17 loads in flight per thread),
// then answer all 300 queries from LDS.
// outT[(b*Cc + c)*Nc + n]  <- coalesced writes (thread index = n)
// ---------------------------------------------------------------------------
__global__ __launch_bounds__(256) void sample_kernel(
    const float* __restrict__ f0, const float* __restrict__ f1,
    const float* __restrict__ f2, const float* __restrict__ f3,
    const float* __restrict__ params, float* __restrict__ outT)
{
    __shared__ float sl[LDS_FLOATS];
    const int bc = blockIdx.x;           // b*Cc + c
    const int t = threadIdx.x;
    const int b = bc >> 8;

    // ---- prefetch this thread's query params (overlaps staging latency) ----
    // thread t handles n0 = t (always < 300) and n1 = t+256 (if t < 44)
    const int q0 = b * Nc + t;
    const bool has2 = (t < Nc - 256);
    const int q1 = q0 + 256;
    float sx0 = params[q0 * 8 + 0];
    float sy0 = params[q0 * 8 + 1];
    float zw0_0 = params[q0 * 8 + 2], zw0_1 = params[q0 * 8 + 3];
    float zw0_2 = params[q0 * 8 + 4], zw0_3 = params[q0 * 8 + 5];
    float sx1 = 0.f, sy1 = 0.f, zw1_0 = 0.f, zw1_1 = 0.f, zw1_2 = 0.f, zw1_3 = 0.f;
    if (has2) {
        sx1 = params[q1 * 8 + 0];
        sy1 = params[q1 * 8 + 1];
        zw1_0 = params[q1 * 8 + 2]; zw1_1 = params[q1 * 8 + 3];
        zw1_2 = params[q1 * 8 + 4]; zw1_3 = params[q1 * 8 + 5];
    }

    // ---- stage: issue ALL loads, then ALL LDS writes ----
    const f32x4* s0 = (const f32x4*)(f0 + (size_t)bc * 10000);  // 2500 vec4
    const f32x4* s1 = (const f32x4*)(f1 + (size_t)bc * 2500);   // 625 vec4
    const float* s2 = f2 + (size_t)bc * 625;                    // 625 dwords
    const float* s3 = f3 + (size_t)bc * 169;                    // 169 dwords

    f32x4 r0[10];
#pragma unroll
    for (int i = 0; i < 9; ++i) r0[i] = s0[t + i * 256];
    if (t < 2500 - 9 * 256) r0[9] = s0[t + 9 * 256];            // t < 196
    f32x4 r1[3];
    r1[0] = s1[t];
    r1[1] = s1[t + 256];
    if (t < 625 - 512) r1[2] = s1[t + 512];                     // t < 113
    float r2[3];
    r2[0] = s2[t];
    r2[1] = s2[t + 256];
    if (t < 113) r2[2] = s2[t + 512];
    float r3 = 0.f;
    if (t < 169) r3 = s3[t];

    f32x4* d0 = (f32x4*)&sl[LVL_OFF[0]];
    f32x4* d1 = (f32x4*)&sl[LVL_OFF[1]];
    float* d2 = &sl[LVL_OFF[2]];
    float* d3 = &sl[LVL_OFF[3]];
#pragma unroll
    for (int i = 0; i < 9; ++i) d0[t + i * 256] = r0[i];
    if (t < 196) d0[t + 9 * 256] = r0[9];
    d1[t] = r1[0];
    d1[t + 256] = r1[1];
    if (t < 113) d1[t + 512] = r1[2];
    d2[t] = r2[0];
    d2[t + 256] = r2[1];
    if (t < 113) d2[t + 512] = r2[2];
    if (t < 169) d3[t] = r3;
    __syncthreads();

    // ---- answer queries from LDS ----
    {
        float acc = zw0_0 * lerp_lds(&sl[LVL_OFF[0]], 100, sx0, sy0)
                  + zw0_1 * lerp_lds(&sl[LVL_OFF[1]],  50, sx0, sy0)
                  + zw0_2 * lerp_lds(&sl[LVL_OFF[2]],  25, sx0, sy0)
                  + zw0_3 * lerp_lds(&sl[LVL_OFF[3]],  13, sx0, sy0);
        outT[(size_t)bc * Nc + t] = acc;
    }
    if (has2) {
        float acc = zw1_0 * lerp_lds(&sl[LVL_OFF[0]], 100, sx1, sy1)
                  + zw1_1 * lerp_lds(&sl[LVL_OFF[1]],  50, sx1, sy1)
                  + zw1_2 * lerp_lds(&sl[LVL_OFF[2]],  25, sx1, sy1)
                  + zw1_3 * lerp_lds(&sl[LVL_OFF[3]],  13, sx1, sy1);
        outT[(size_t)bc * Nc + t + 256] = acc;
    }
}

// ---------------------------------------------------------------------------
// Kernel 3: one block per query. Read 256 channel values (strided dwords,
// L2/L3-absorbed: outT footprint 2.46 MB), broadcast over P with NT float4.
// ---------------------------------------------------------------------------
__global__ __launch_bounds__(256) void broadcast_kernel(
    const float* __restrict__ outT, float* __restrict__ out)
{
    __shared__ float sval[Cc];
    const int q = blockIdx.x;            // b*Nc + n
    const int b = q / Nc;
    const int n = q - b * Nc;
    const int c = threadIdx.x;
    sval[c] = outT[((size_t)(b * Cc + c)) * Nc + n];
    __syncthreads();

    const int wave = threadIdx.x >> 6;
    const int c4 = (threadIdx.x & 63) * 4;
    f32x4 val = *(const f32x4*)&sval[c4];
    float* obase = out + (size_t)q * (Pc * Cc) + c4;
#pragma unroll
    for (int p = wave; p < Pc; p += 4) {
        __builtin_nontemporal_store(val, (f32x4*)(obase + p * Cc));
    }
}

// ---------------------------------------------------------------------------
// Fallback: proven single-kernel path (if ws too small). Not expected to run.
// ---------------------------------------------------------------------------
__global__ __launch_bounds__(256) void sampling3d_fallback(
    const float* __restrict__ f0, const float* __restrict__ f1,
    const float* __restrict__ f2, const float* __restrict__ f3,
    const float* __restrict__ qpos, const float* __restrict__ qcont,
    const float* __restrict__ Woff, const float* __restrict__ boff,
    const float* __restrict__ sigma, float* __restrict__ out)
{
    const int q = blockIdx.x;
    const int b = q / Nc;
    const int c = threadIdx.x;
    float qc = qcont[q * Cc + c];
    float p0 = qc * Woff[c * 3 + 0];
    float p1 = qc * Woff[c * 3 + 1];
    float p2 = qc * Woff[c * 3 + 2];
#pragma unroll
    for (int off = 32; off > 0; off >>= 1) {
        p0 += __shfl_down(p0, off, 64);
        p1 += __shfl_down(p1, off, 64);
        p2 += __shfl_down(p2, off, 64);
    }
    __shared__ float red[4][3];
    __shared__ float par[8];
    __shared__ float accs[Cc];
    const int wave = threadIdx.x >> 6;
    if ((threadIdx.x & 63) == 0) { red[wave][0] = p0; red[wave][1] = p1; red[wave][2] = p2; }
    __syncthreads();
    if (threadIdx.x == 0) {
        float dx = red[0][0] + red[1][0] + red[2][0] + red[3][0] + boff[0];
        float dy = red[0][1] + red[1][1] + red[2][1] + red[3][1] + boff[1];
        float dz = red[0][2] + red[1][2] + red[2][2] + red[3][2] + boff[2];
        float x = qpos[q * 4 + 0], y = qpos[q * 4 + 1];
        float z = qpos[q * 4 + 2], r = qpos[q * 4 + 3];
        float sx = x + dx * exp2f(z - r);
        float sy = y + dy * exp2f(z + r);
        float sz = z + dz;
        float sg = sigma[0];
        float inv = 1.0f / (2.0f * sg * sg);
        float e[4]; float s = 0.f;
#pragma unroll
        for (int l = 0; l < 4; ++l) {
            float d = sz - (float)l;
            float w = __expf(-d * d * inv);
            e[l] = __expf(w);
            s += e[l];
        }
        float rs = 1.0f / s;
        par[0] = sx; par[1] = sy;
#pragma unroll
        for (int l = 0; l < 4; ++l) par[2 + l] = e[l] * rs;
    }
    __syncthreads();
    const float sx = par[0];
    const float sy = par[1];
    const float* const fs[4] = {f0, f1, f2, f3};
    const int HWs[4] = {100, 50, 25, 13};
    float acc = 0.f;
#pragma unroll
    for (int l = 0; l < 4; ++l) {
        const int W = HWs[l];
        float px = fminf(fmaxf(sx - 0.5f, 0.f), (float)(W - 1));
        float py = fminf(fmaxf(sy - 0.5f, 0.f), (float)(W - 1));
        float x0f = floorf(px), y0f = floorf(py);
        float wx = px - x0f, wy = py - y0f;
        int x0 = (int)x0f, y0 = (int)y0f;
        int x1 = min(x0 + 1, W - 1), y1 = min(y0 + 1, W - 1);
        const float* base = fs[l] + (size_t)((b * Cc + c) * W) * W;
        float v00 = base[y0 * W + x0];
        float v01 = base[y0 * W + x1];
        float v10 = base[y1 * W + x0];
        float v11 = base[y1 * W + x1];
        float top = v00 + wx * (v01 - v00);
        float bot = v10 + wx * (v11 - v10);
        acc += par[2 + l] * (top + wy * (bot - top));
    }
    accs[c] = acc;
    __syncthreads();
    const int c4 = (threadIdx.x & 63) * 4;
    f32x4 val = *(const f32x4*)&accs[c4];
    float* obase = out + (size_t)q * (Pc * Cc) + c4;
#pragma unroll
    for (int p = wave; p < Pc; p += 4) {
        __builtin_nontemporal_store(val, (f32x4*)(obase + p * Cc));
    }
}

extern "C" void kernel_launch(void* const* d_in, const int* in_sizes, int n_in,
                              void* d_out, int out_size, void* d_ws, size_t ws_size,
                              hipStream_t stream) {
    const float* f0    = (const float*)d_in[0];
    const float* f1    = (const float*)d_in[1];
    const float* f2    = (const float*)d_in[2];
    const float* f3    = (const float*)d_in[3];
    const float* qpos  = (const float*)d_in[4];
    const float* qcont = (const float*)d_in[5];
    const float* Woff  = (const float*)d_in[6];
    const float* boff  = (const float*)d_in[7];
    const float* sigma = (const float*)d_in[8];
    float* out = (float*)d_out;

    const size_t params_bytes = (size_t)Bc * Nc * 8 * sizeof(float);      // 76.8 KB
    const size_t outT_bytes   = (size_t)Bc * Cc * Nc * sizeof(float);     // 2.46 MB

    if (ws_size >= params_bytes + outT_bytes) {
        float* params = (float*)d_ws;
        float* outT   = (float*)((char*)d_ws + params_bytes);
        params_kernel<<<Bc * Nc, 256, 0, stream>>>(qpos, qcont, Woff, boff, sigma, params);
        sample_kernel<<<Bc * Cc, 256, 0, stream>>>(f0, f1, f2, f3, params, outT);
        broadcast_kernel<<<Bc * Nc, 256, 0, stream>>>(outT, out);
    } else {
        sampling3d_fallback<<<Bc * Nc, 256, 0, stream>>>(
            f0, f1, f2, f3, qpos, qcont, Woff, boff, sigma, out);
    }
}

// Round 6
// 191.142 us; speedup vs baseline: 1.0408x; 1.0015x over previous
//
#include <hip/hip_runtime.h>

// Problem constants (from reference setup_inputs)
constexpr int Bc = 8;
constexpr int Nc = 300;
constexpr int Cc = 256;
constexpr int Pc = 32;

typedef float f32x4 __attribute__((ext_vector_type(4)));

// Level geometry: 100^2, 50^2, 25^2, 13^2 ; floats/slice 10000, 2500, 625, 169
constexpr int LVL_OFF[4] = {0, 10000, 12500, 13125};
constexpr int LDS_FLOATS = 13294;   // 53,176 B

// ---- async global->LDS DMA (zero VGPR data footprint) ----
// LDS dest semantics: wave-uniform base + lane*size (m104). Our layout is flat
// and contiguous in lane order, so this is exact.
__device__ __forceinline__ void gl_lds16(const void* g, void* l) {
    __builtin_amdgcn_global_load_lds(
        (const __attribute__((address_space(1))) void*)g,
        (__attribute__((address_space(3))) void*)l, 16, 0, 0);
}
__device__ __forceinline__ void gl_lds4(const void* g, void* l) {
    __builtin_amdgcn_global_load_lds(
        (const __attribute__((address_space(1))) void*)g,
        (__attribute__((address_space(3))) void*)l, 4, 0, 0);
}

// ---------------------------------------------------------------------------
// Kernel 1: per-query params. One block per query q = b*N+n.
// params[q*8 + {0:sx, 1:sy, 2..5: zw[l]}]
// ---------------------------------------------------------------------------
__global__ __launch_bounds__(256) void params_kernel(
    const float* __restrict__ qpos, const float* __restrict__ qcont,
    const float* __restrict__ Woff, const float* __restrict__ boff,
    const float* __restrict__ sigma, float* __restrict__ params)
{
    const int q = blockIdx.x;
    const int c = threadIdx.x;
    float qc = qcont[q * Cc + c];
    float p0 = qc * Woff[c * 3 + 0];
    float p1 = qc * Woff[c * 3 + 1];
    float p2 = qc * Woff[c * 3 + 2];
#pragma unroll
    for (int off = 32; off > 0; off >>= 1) {
        p0 += __shfl_down(p0, off, 64);
        p1 += __shfl_down(p1, off, 64);
        p2 += __shfl_down(p2, off, 64);
    }
    __shared__ float red[4][3];
    const int wave = threadIdx.x >> 6;
    if ((threadIdx.x & 63) == 0) {
        red[wave][0] = p0; red[wave][1] = p1; red[wave][2] = p2;
    }
    __syncthreads();
    if (threadIdx.x == 0) {
        float dx = red[0][0] + red[1][0] + red[2][0] + red[3][0] + boff[0];
        float dy = red[0][1] + red[1][1] + red[2][1] + red[3][1] + boff[1];
        float dz = red[0][2] + red[1][2] + red[2][2] + red[3][2] + boff[2];
        float x = qpos[q * 4 + 0];
        float y = qpos[q * 4 + 1];
        float z = qpos[q * 4 + 2];
        float r = qpos[q * 4 + 3];
        float sx = x + dx * exp2f(z - r);
        float sy = y + dy * exp2f(z + r);
        float sz = z + dz;
        float sg = sigma[0];
        float inv = 1.0f / (2.0f * sg * sg);
        float e[4];
        float s = 0.f;
#pragma unroll
        for (int l = 0; l < 4; ++l) {
            float d = sz - (float)l;
            float w = __expf(-d * d * inv);   // gaussian weight in (0,1]
            e[l] = __expf(w);                 // softmax numerator of that weight
            s += e[l];
        }
        float rs = 1.0f / s;
        params[q * 8 + 0] = sx;
        params[q * 8 + 1] = sy;
#pragma unroll
        for (int l = 0; l < 4; ++l) params[q * 8 + 2 + l] = e[l] * rs;
    }
}

// bilinear from an LDS slice, border padding, align_corners=False
__device__ __forceinline__ float lerp_lds(const float* __restrict__ base, int W,
                                          float sx, float sy)
{
    float px = fminf(fmaxf(sx - 0.5f, 0.f), (float)(W - 1));
    float py = fminf(fmaxf(sy - 0.5f, 0.f), (float)(W - 1));
    float x0f = floorf(px);
    float y0f = floorf(py);
    float wx = px - x0f;
    float wy = py - y0f;
    int x0 = (int)x0f;
    int y0 = (int)y0f;
    int x1 = min(x0 + 1, W - 1);
    int y1 = min(y0 + 1, W - 1);
    float v00 = base[y0 * W + x0];
    float v01 = base[y0 * W + x1];
    float v10 = base[y1 * W + x0];
    float v11 = base[y1 * W + x1];
    float top = v00 + wx * (v01 - v00);
    float bot = v10 + wx * (v11 - v10);
    return top + wy * (bot - top);
}

// ---------------------------------------------------------------------------
// Kernel 2: one block per (b,c). Stage the 4 feature slices into LDS with
// async global_load_lds DMA (fire-and-forget; drained by __syncthreads),
// then answer all 300 queries from LDS.
// outT[(b*Cc + c)*Nc + n]  <- coalesced writes (thread index = n)
// ---------------------------------------------------------------------------
__global__ __launch_bounds__(256) void sample_kernel(
    const float* __restrict__ f0, const float* __restrict__ f1,
    const float* __restrict__ f2, const float* __restrict__ f3,
    const float* __restrict__ params, float* __restrict__ outT)
{
    __shared__ float sl[LDS_FLOATS];
    const int bc = blockIdx.x;           // b*Cc + c
    const int t = threadIdx.x;
    const int b = bc >> 8;
    const int wave = t >> 6;
    const int lane = t & 63;

    // ---- prefetch this thread's query params (overlaps staging latency) ----
    const int q0 = b * Nc + t;
    const bool has2 = (t < Nc - 256);
    const int q1 = q0 + 256;
    float sx0 = params[q0 * 8 + 0];
    float sy0 = params[q0 * 8 + 1];
    float zw0_0 = params[q0 * 8 + 2], zw0_1 = params[q0 * 8 + 3];
    float zw0_2 = params[q0 * 8 + 4], zw0_3 = params[q0 * 8 + 5];
    float sx1 = 0.f, sy1 = 0.f, zw1_0 = 0.f, zw1_1 = 0.f, zw1_2 = 0.f, zw1_3 = 0.f;
    if (has2) {
        sx1 = params[q1 * 8 + 0];
        sy1 = params[q1 * 8 + 1];
        zw1_0 = params[q1 * 8 + 2]; zw1_1 = params[q1 * 8 + 3];
        zw1_2 = params[q1 * 8 + 4]; zw1_3 = params[q1 * 8 + 5];
    }

    // ---- async staging: all ops fire-and-forget, one drain at the barrier ----
    // level 0: 40000 B, 16B-aligned (bc*40000). 39 chunks of 1024 B + 64 B tail.
    {
        const char* g0 = (const char*)(f0 + (size_t)bc * 10000);
        char* l0 = (char*)&sl[LVL_OFF[0]];
        for (int i = wave; i < 39; i += 4)
            gl_lds16(g0 + i * 1024 + lane * 16, l0 + i * 1024);
        if (wave == 3 && lane < 4)
            gl_lds16(g0 + 39 * 1024 + lane * 16, l0 + 39 * 1024);
    }
    // level 1: 10000 B, 16B-aligned (bc*10000). 9 chunks + 784 B tail (49 lanes).
    {
        const char* g1 = (const char*)(f1 + (size_t)bc * 2500);
        char* l1 = (char*)&sl[LVL_OFF[1]];
        for (int i = wave; i < 9; i += 4)
            gl_lds16(g1 + i * 1024 + lane * 16, l1 + i * 1024);
        if (wave == 2 && lane < 49)
            gl_lds16(g1 + 9 * 1024 + lane * 16, l1 + 9 * 1024);
    }
    // level 2: 625 dwords, only 4B-aligned (bc*2500 B) -> width-4 DMA.
    // 9 ops of 256 B + 49-lane tail.
    {
        const char* g2 = (const char*)(f2 + (size_t)bc * 625);
        char* l2 = (char*)&sl[LVL_OFF[2]];
        for (int i = wave; i < 9; i += 4)
            gl_lds4(g2 + i * 256 + lane * 4, l2 + i * 256);
        if (wave == 1 && lane < 49)
            gl_lds4(g2 + 9 * 256 + lane * 4, l2 + 9 * 256);
    }
    // level 3: 169 dwords -> width-4 DMA. 2 ops + 41-lane tail.
    {
        const char* g3 = (const char*)(f3 + (size_t)bc * 169);
        char* l3 = (char*)&sl[LVL_OFF[3]];
        for (int i = wave; i < 2; i += 4)
            gl_lds4(g3 + i * 256 + lane * 4, l3 + i * 256);
        if (wave == 3 && lane < 41)
            gl_lds4(g3 + 2 * 256 + lane * 4, l3 + 2 * 256);
    }
    __syncthreads();   // drains vmcnt(0): all DMA + params loads complete

    // ---- answer queries from LDS ----
    {
        float acc = zw0_0 * lerp_lds(&sl[LVL_OFF[0]], 100, sx0, sy0)
                  + zw0_1 * lerp_lds(&sl[LVL_OFF[1]],  50, sx0, sy0)
                  + zw0_2 * lerp_lds(&sl[LVL_OFF[2]],  25, sx0, sy0)
                  + zw0_3 * lerp_lds(&sl[LVL_OFF[3]],  13, sx0, sy0);
        outT[(size_t)bc * Nc + t] = acc;
    }
    if (has2) {
        float acc = zw1_0 * lerp_lds(&sl[LVL_OFF[0]], 100, sx1, sy1)
                  + zw1_1 * lerp_lds(&sl[LVL_OFF[1]],  50, sx1, sy1)
                  + zw1_2 * lerp_lds(&sl[LVL_OFF[2]],  25, sx1, sy1)
                  + zw1_3 * lerp_lds(&sl[LVL_OFF[3]],  13, sx1, sy1);
        outT[(size_t)bc * Nc + t + 256] = acc;
    }
}

// ---------------------------------------------------------------------------
// Kernel 3: one block per query. Read 256 channel values (strided dwords,
// L2/L3-absorbed: outT footprint 2.46 MB), broadcast over P with NT float4.
// ---------------------------------------------------------------------------
__global__ __launch_bounds__(256) void broadcast_kernel(
    const float* __restrict__ outT, float* __restrict__ out)
{
    __shared__ float sval[Cc];
    const int q = blockIdx.x;            // b*Nc + n
    const int b = q / Nc;
    const int n = q - b * Nc;
    const int c = threadIdx.x;
    sval[c] = outT[((size_t)(b * Cc + c)) * Nc + n];
    __syncthreads();

    const int wave = threadIdx.x >> 6;
    const int c4 = (threadIdx.x & 63) * 4;
    f32x4 val = *(const f32x4*)&sval[c4];
    float* obase = out + (size_t)q * (Pc * Cc) + c4;
#pragma unroll
    for (int p = wave; p < Pc; p += 4) {
        __builtin_nontemporal_store(val, (f32x4*)(obase + p * Cc));
    }
}

// ---------------------------------------------------------------------------
// Fallback: proven single-kernel path (if ws too small). Not expected to run.
// ---------------------------------------------------------------------------
__global__ __launch_bounds__(256) void sampling3d_fallback(
    const float* __restrict__ f0, const float* __restrict__ f1,
    const float* __restrict__ f2, const float* __restrict__ f3,
    const float* __restrict__ qpos, const float* __restrict__ qcont,
    const float* __restrict__ Woff, const float* __restrict__ boff,
    const float* __restrict__ sigma, float* __restrict__ out)
{
    const int q = blockIdx.x;
    const int b = q / Nc;
    const int c = threadIdx.x;
    float qc = qcont[q * Cc + c];
    float p0 = qc * Woff[c * 3 + 0];
    float p1 = qc * Woff[c * 3 + 1];
    float p2 = qc * Woff[c * 3 + 2];
#pragma unroll
    for (int off = 32; off > 0; off >>= 1) {
        p0 += __shfl_down(p0, off, 64);
        p1 += __shfl_down(p1, off, 64);
        p2 += __shfl_down(p2, off, 64);
    }
    __shared__ float red[4][3];
    __shared__ float par[8];
    __shared__ float accs[Cc];
    const int wave = threadIdx.x >> 6;
    if ((threadIdx.x & 63) == 0) { red[wave][0] = p0; red[wave][1] = p1; red[wave][2] = p2; }
    __syncthreads();
    if (threadIdx.x == 0) {
        float dx = red[0][0] + red[1][0] + red[2][0] + red[3][0] + boff[0];
        float dy = red[0][1] + red[1][1] + red[2][1] + red[3][1] + boff[1];
        float dz = red[0][2] + red[1][2] + red[2][2] + red[3][2] + boff[2];
        float x = qpos[q * 4 + 0], y = qpos[q * 4 + 1];
        float z = qpos[q * 4 + 2], r = qpos[q * 4 + 3];
        float sx = x + dx * exp2f(z - r);
        float sy = y + dy * exp2f(z + r);
        float sz = z + dz;
        float sg = sigma[0];
        float inv = 1.0f / (2.0f * sg * sg);
        float e[4]; float s = 0.f;
#pragma unroll
        for (int l = 0; l < 4; ++l) {
            float d = sz - (float)l;
            float w = __expf(-d * d * inv);
            e[l] = __expf(w);
            s += e[l];
        }
        float rs = 1.0f / s;
        par[0] = sx; par[1] = sy;
#pragma unroll
        for (int l = 0; l < 4; ++l) par[2 + l] = e[l] * rs;
    }
    __syncthreads();
    const float sx = par[0];
    const float sy = par[1];
    const float* const fs[4] = {f0, f1, f2, f3};
    const int HWs[4] = {100, 50, 25, 13};
    float acc = 0.f;
#pragma unroll
    for (int l = 0; l < 4; ++l) {
        const int W = HWs[l];
        float px = fminf(fmaxf(sx - 0.5f, 0.f), (float)(W - 1));
        float py = fminf(fmaxf(sy - 0.5f, 0.f), (float)(W - 1));
        float x0f = floorf(px), y0f = floorf(py);
        float wx = px - x0f, wy = py - y0f;
        int x0 = (int)x0f, y0 = (int)y0f;
        int x1 = min(x0 + 1, W - 1), y1 = min(y0 + 1, W - 1);
        const float* base = fs[l] + (size_t)((b * Cc + c) * W) * W;
        float v00 = base[y0 * W + x0];
        float v01 = base[y0 * W + x1];
        float v10 = base[y1 * W + x0];
        float v11 = base[y1 * W + x1];
        float top = v00 + wx * (v01 - v00);
        float bot = v10 + wx * (v11 - v10);
        acc += par[2 + l] * (top + wy * (bot - top));
    }
    accs[c] = acc;
    __syncthreads();
    const int c4 = (threadIdx.x & 63) * 4;
    f32x4 val = *(const f32x4*)&accs[c4];
    float* obase = out + (size_t)q * (Pc * Cc) + c4;
#pragma unroll
    for (int p = wave; p < Pc; p += 4) {
        __builtin_nontemporal_store(val, (f32x4*)(obase + p * Cc));
    }
}

extern "C" void kernel_launch(void* const* d_in, const int* in_sizes, int n_in,
                              void* d_out, int out_size, void* d_ws, size_t ws_size,
                              hipStream_t stream) {
    const float* f0    = (const float*)d_in[0];
    const float* f1    = (const float*)d_in[1];
    const float* f2    = (const float*)d_in[2];
    const float* f3    = (const float*)d_in[3];
    const float* qpos  = (const float*)d_in[4];
    const float* qcont = (const float*)d_in[5];
    const float* Woff  = (const float*)d_in[6];
    const float* boff  = (const float*)d_in[7];
    const float* sigma = (const float*)d_in[8];
    float* out = (float*)d_out;

    const size_t params_bytes = (size_t)Bc * Nc * 8 * sizeof(float);      // 76.8 KB
    const size_t outT_bytes   = (size_t)Bc * Cc * Nc * sizeof(float);     // 2.46 MB

    if (ws_size >= params_bytes + outT_bytes) {
        float* params = (float*)d_ws;
        float* outT   = (float*)((char*)d_ws + params_bytes);
        params_kernel<<<Bc * Nc, 256, 0, stream>>>(qpos, qcont, Woff, boff, sigma, params);
        sample_kernel<<<Bc * Cc, 256, 0, stream>>>(f0, f1, f2, f3, params, outT);
        broadcast_kernel<<<Bc * Nc, 256, 0, stream>>>(outT, out);
    } else {
        sampling3d_fallback<<<Bc * Nc, 256, 0, stream>>>(
            f0, f1, f2, f3, qpos, qcont, Woff, boff, sigma, out);
    }
}